// Round 2
// baseline (529.688 us; speedup 1.0000x reference)
//
#include <hip/hip_runtime.h>
#include <hip/hip_bf16.h>
#include <stdint.h>

#define IN_F 4096
#define OUT_F 11008
#define TOKENS 32
#define NELEM_W (OUT_F * IN_F)        // 45088768 weights, ~180 MB fp32
#define OUT_ELEMS (TOKENS * OUT_F)    // 352256

typedef __attribute__((ext_vector_type(8))) __bf16 bf16x8;
typedef __attribute__((ext_vector_type(4))) float  f32x4;

// d_ws layout (bytes):
//   [0, 64):     scalars: u[0]=exc_count, u[1]=arrive, f[2]=thr (exact), f[3]=scale
//   [64,+256K):  xb — x converted to bf16
//   [262208):    spart — 256 sample-pass per-block partials (plain stores)
//   [263232):    apart — 1376 per-gemm-block sum(|w|) partials
//   [268736):    gpart — 2 x 352256 f32 split-K partials (fixup patches half 0)
//   [3086784):   exception index buffer, uint32 = row*4096+col, 4 MB
#define XB_OFF    64
#define SPART_OFF 262208
#define APART_OFF 263232
#define GPART_OFF 268736
#define EXC_OFF   3086784
#define EXC_CAP   1048576u

#define N_SAMPLE_F 1048576.0f   // 256 blocks * 4 waves * 4 float4 * 64 lanes * 4
#define DELTA 0.004f            // band half-width ~5.3 sigma of thr_hat error
#define GEMM_BLOCKS 1376

// fp32 -> bf16 bits (round-to-nearest-even), result in low 16
__device__ __forceinline__ uint32_t bfr(float v) {
    uint32_t u = __float_as_uint(v);
    uint32_t r = u + 0x7FFFu + ((u >> 16) & 1u);
    return r >> 16;
}

// provisional threshold from sampled |w| sum — must be bit-identical in
// gemm and fixup: both call this on the same deterministically-reduced sum.
__device__ __forceinline__ float thr_hat_from(float ssum) {
    float m = ssum * (1.0f / N_SAMPLE_F);
    if (m < 1e-5f) m = 1e-5f;
    return 0.7f * m;
}

// Deterministic fixed-shape reduction of the 256 sample partials.
// Identical instruction sequence in every block of every kernel that calls
// it -> bit-identical result everywhere. Threads >=128 just sync.
__device__ __forceinline__ float block_sample_sum(const float* __restrict__ spart,
                                                  float* buf, int tid) {
    if (tid < 128) buf[tid] = spart[tid] + spart[tid + 128];
    __syncthreads();
#pragma unroll
    for (int s = 64; s > 0; s >>= 1) {
        if (tid < s) buf[tid] = buf[tid] + buf[tid + s];
        __syncthreads();
    }
    return buf[0];
}

// ---------------- pass 0: sampled partials + x->bf16 + counter zeroing ---------
__global__ __launch_bounds__(256) void sample_xcvt_kernel(const float* __restrict__ w,
                                                          const float* __restrict__ x,
                                                          float* __restrict__ spart,
                                                          uint4* __restrict__ xb,
                                                          unsigned int* __restrict__ exc_cnt,
                                                          unsigned int* __restrict__ arrive) {
    if (blockIdx.x >= 256) {
        if (blockIdx.x == 256 && threadIdx.x == 0) { *exc_cnt = 0u; *arrive = 0u; }
        int i = (blockIdx.x - 256) * 256 + threadIdx.x;
        const float4* x4 = (const float4*)x;
        float4 a0 = x4[i * 2];
        float4 a1 = x4[i * 2 + 1];
        uint4 o;
        o.x = bfr(a0.x) | (bfr(a0.y) << 16);
        o.y = bfr(a0.z) | (bfr(a0.w) << 16);
        o.z = bfr(a1.x) | (bfr(a1.y) << 16);
        o.w = bfr(a1.z) | (bfr(a1.w) << 16);
        xb[i] = o;
        return;
    }
    const int wv   = threadIdx.x >> 6;
    const int lane = threadIdx.x & 63;
    const int wid  = blockIdx.x * 4 + wv;
    const float4* w4 = (const float4*)w;
    size_t base = (size_t)wid * 11008 + lane;
    float s = 0.f;
#pragma unroll
    for (int r = 0; r < 4; ++r) {
        float4 v = w4[base + (size_t)r * 2752];
        s += __builtin_fabsf(v.x) + __builtin_fabsf(v.y) +
             __builtin_fabsf(v.z) + __builtin_fabsf(v.w);
    }
    for (int off = 32; off > 0; off >>= 1) s += __shfl_down(s, off, 64);
    __shared__ float ws4[4];
    if (lane == 0) ws4[wv] = s;
    __syncthreads();
    if (threadIdx.x == 0) spart[blockIdx.x] = ws4[0] + ws4[1] + ws4[2] + ws4[3];
}

// ---------------- ternarize helpers ----------------
__device__ __forceinline__ uint32_t tern1(float v, float thr) {
    uint32_t u  = __float_as_uint(v);
    uint32_t pm = (u & 0x80000000u) | 0x3F800000u;   // +-1.0f
    return (__builtin_fabsf(v) > thr) ? pm : 0u;
}

__device__ __forceinline__ uint2 tern4(float4 b, float thr) {
    uint32_t q0 = tern1(b.x, thr), q1 = tern1(b.y, thr);
    uint32_t q2 = tern1(b.z, thr), q3 = tern1(b.w, thr);
    uint2 r;
    r.x = __builtin_amdgcn_perm(q1, q0, 0x07060302u);   // lo16=q0.hi16, hi16=q1.hi16
    r.y = __builtin_amdgcn_perm(q3, q2, 0x07060302u);
    return r;
}

// ---------------- pass 1: single-read ternary GEMM (round-0 proven shape) ------
// Grid: 688 o-groups x 2 K-halves = 1376 blocks of 128 (2 waves), all resident.
// Additions vs round-0: (a) branchless 256-bit/thread exception mask
// (cmp+cndmask+or, no branches, no DS ops in the loop), (b) exact |w| partial
// via abs-add, (c) post-loop index flush, (d) last-block finalize.
#define CHUNKS 16
#define WAVE_LDS 2304          // 16 rows * 144 B
#define SMEM_BYTES 4608        // 2 waves; also covers 2*512*4 reduce buf

__global__ __launch_bounds__(128, 3) void ternary_gemm(const float* __restrict__ w,
                                                       const float* __restrict__ spart,
                                                       const __bf16* __restrict__ xb,
                                                       float* __restrict__ gpart,
                                                       float* __restrict__ apart,
                                                       unsigned int* __restrict__ excg,
                                                       unsigned int* __restrict__ exc_cnt,
                                                       unsigned int* __restrict__ arrive,
                                                       float* __restrict__ wsf) {
    __shared__ char smem_raw[SMEM_BYTES];
    __shared__ float thbuf[128];
    __shared__ float wsum2[2];
    __shared__ unsigned int lastflag;

    const int og   = blockIdx.x >> 1;
    const int kh   = blockIdx.x & 1;
    const int tid  = threadIdx.x;
    const int wv   = tid >> 6;
    const int lane = tid & 63;
    const int col  = lane & 15;     // fragment: output col in group / token
    const int quad = lane >> 4;     // fragment k sub-block; staging row group
    const int rlan = lane & 15;     // staging: 16-B slot within a row

    const int kw    = kh * 2048 + wv * 1024;
    const int obase = og * 16 + quad;          // row for r=0; +4r for r=1..3

    const float* wp = w + (size_t)obase * IN_F + kw + rlan * 4;
    char* stage = smem_raw + wv * WAVE_LDS;
    char* wr    = stage + quad * 144 + rlan * 8;   // + j*576 per staging instr
    const char* rd = stage + col * 144;
    const __bf16* xq = xb + (size_t)col * IN_F + kw + quad * 8;

    f32x4 acc0 = {0.f, 0.f, 0.f, 0.f};
    f32x4 acc1 = {0.f, 0.f, 0.f, 0.f};
    float sab = 0.f;
    uint32_t em[8] = {0u, 0u, 0u, 0u, 0u, 0u, 0u, 0u};

    float4 wb[2][4];
    bf16x8 xv[2][4];

    // issue first prefetches, THEN the th-reduction (hides its 8 barriers)
#pragma unroll
    for (int c = 0; c < 2; ++c) {
        const float*  np = wp + c * 64;
        const __bf16* xn = xq + c * 64;
        wb[c][0] = *(const float4*)(np);
        wb[c][1] = *(const float4*)(np + 4 * IN_F);
        wb[c][2] = *(const float4*)(np + 8 * IN_F);
        wb[c][3] = *(const float4*)(np + 12 * IN_F);
        xv[c][0] = *(const bf16x8*)(xn);
        xv[c][1] = *(const bf16x8*)(xn + 32);
        xv[c][2] = *(const bf16x8*)(xn + 16 * IN_F);
        xv[c][3] = *(const bf16x8*)(xn + 16 * IN_F + 32);
    }

    const float th  = thr_hat_from(block_sample_sum(spart, thbuf, tid));
    const float eps = th * DELTA;

// branchless: one bit per element, constant word/bit under full unroll
#define EXCEL(f, wd, bit)                                                      \
    em[wd] |= (__builtin_fabsf(__builtin_fabsf(f) - th) < eps) ? (1u << (bit)) : 0u;

#define PROC4(vv, wd, bb)                                                      \
    sab += __builtin_fabsf(vv.x) + __builtin_fabsf(vv.y) +                     \
           __builtin_fabsf(vv.z) + __builtin_fabsf(vv.w);                      \
    EXCEL(vv.x, wd, (bb) + 0)                                                  \
    EXCEL(vv.y, wd, (bb) + 1)                                                  \
    EXCEL(vv.z, wd, (bb) + 2)                                                  \
    EXCEL(vv.w, wd, (bb) + 3)

#define GEMM_BODY(c, cur)                                                      \
    {                                                                          \
        uint2 t0 = tern4(wb[cur][0], th);                                      \
        uint2 t1 = tern4(wb[cur][1], th);                                      \
        uint2 t2 = tern4(wb[cur][2], th);                                      \
        uint2 t3 = tern4(wb[cur][3], th);                                      \
        *(uint2*)(wr)        = t0;                                             \
        *(uint2*)(wr + 576)  = t1;                                             \
        *(uint2*)(wr + 1152) = t2;                                             \
        *(uint2*)(wr + 1728) = t3;                                             \
        PROC4(wb[cur][0], ((c) >> 1), (((c) & 1) * 16 + 0))                    \
        PROC4(wb[cur][1], ((c) >> 1), (((c) & 1) * 16 + 4))                    \
        PROC4(wb[cur][2], ((c) >> 1), (((c) & 1) * 16 + 8))                    \
        PROC4(wb[cur][3], ((c) >> 1), (((c) & 1) * 16 + 12))                   \
        bf16x8 a00 = xv[cur][0], a01 = xv[cur][1];                             \
        bf16x8 a10 = xv[cur][2], a11 = xv[cur][3];                             \
        if ((c) + 2 < CHUNKS) {                                                \
            const float*  np = wp + ((c) + 2) * 64;                            \
            const __bf16* xn = xq + ((c) + 2) * 64;                            \
            wb[cur][0] = *(const float4*)(np);                                 \
            wb[cur][1] = *(const float4*)(np + 4 * IN_F);                      \
            wb[cur][2] = *(const float4*)(np + 8 * IN_F);                      \
            wb[cur][3] = *(const float4*)(np + 12 * IN_F);                     \
            xv[cur][0] = *(const bf16x8*)(xn);                                 \
            xv[cur][1] = *(const bf16x8*)(xn + 32);                            \
            xv[cur][2] = *(const bf16x8*)(xn + 16 * IN_F);                     \
            xv[cur][3] = *(const bf16x8*)(xn + 16 * IN_F + 32);                \
        }                                                                      \
        bf16x8 bw0 = *(const bf16x8*)(rd + quad * 16);                         \
        bf16x8 bw1 = *(const bf16x8*)(rd + 64 + quad * 16);                    \
        acc0 = __builtin_amdgcn_mfma_f32_16x16x32_bf16(a00, bw0, acc0, 0, 0, 0); \
        acc1 = __builtin_amdgcn_mfma_f32_16x16x32_bf16(a10, bw0, acc1, 0, 0, 0); \
        acc0 = __builtin_amdgcn_mfma_f32_16x16x32_bf16(a01, bw1, acc0, 0, 0, 0); \
        acc1 = __builtin_amdgcn_mfma_f32_16x16x32_bf16(a11, bw1, acc1, 0, 0, 0); \
    }

#pragma unroll
    for (int c = 0; c < CHUNKS; c += 2) {
        GEMM_BODY(c, 0)
        GEMM_BODY(c + 1, 1)
    }
#undef GEMM_BODY
#undef PROC4
#undef EXCEL

    // exact |w| partial: wave shuffle reduce, cross-wave via LDS
    for (int off = 32; off > 0; off >>= 1) sab += __shfl_down(sab, off, 64);
    if (lane == 0) wsum2[wv] = sab;

    __syncthreads();                     // also guards smem_raw reuse below
    if (tid == 0) apart[blockIdx.x] = wsum2[0] + wsum2[1];

    float* red   = (float*)smem_raw;
    float* basef = red + wv * 512;
#pragma unroll
    for (int r = 0; r < 4; ++r) basef[r * 64 + lane]       = acc0[r];
#pragma unroll
    for (int r = 0; r < 4; ++r) basef[256 + r * 64 + lane] = acc1[r];
    __syncthreads();

    // 512 outputs (32 tokens x 16 cols), summed over 2 waves
    float* gp = gpart + (size_t)kh * OUT_ELEMS;
    for (int p = tid; p < 512; p += 128) {
        int t = p >> 4, cc2 = p & 15;
        int a = t >> 4;
        int q = (t >> 2) & 3;
        int r = t & 3;
        int idx = a * 256 + r * 64 + q * 16 + cc2;
        gp[(size_t)t * OUT_F + og * 16 + cc2] = red[idx] + red[512 + idx];
    }

    // flush exception indices (wave-aggregated atomic; ~0.5 bits/thread)
    unsigned cnt = 0;
#pragma unroll
    for (int ww = 0; ww < 8; ++ww) cnt += (unsigned)__popc(em[ww]);
    unsigned gbase = atomicAdd(exc_cnt, cnt);
#pragma unroll
    for (int ww = 0; ww < 8; ++ww) {
        unsigned m = em[ww];
        while (m) {
            int b = __ffs(m) - 1;
            m &= m - 1;
            int cc3 = 2 * ww + (b >> 4);
            int rr  = (b >> 2) & 3;
            int ee  = b & 3;
            unsigned row = (unsigned)(obase + 4 * rr);
            unsigned cl  = (unsigned)(kw + cc3 * 64 + rlan * 4 + ee);
            if (gbase < EXC_CAP) excg[gbase] = (row << 12) | cl;
            ++gbase;
        }
    }

    // last-block finalize: exact mean -> thr/scale (saves a dispatch)
    __threadfence();
    if (tid == 0) lastflag = (atomicAdd(arrive, 1u) == (unsigned)(GEMM_BLOCKS - 1)) ? 1u : 0u;
    __syncthreads();
    if (lastflag) {
        __threadfence();
        float s = 0.f;
        for (int k = tid; k < GEMM_BLOCKS; k += 128) s += apart[k];
        for (int off = 32; off > 0; off >>= 1) s += __shfl_down(s, off, 64);
        if (lane == 0) wsum2[wv] = s;
        __syncthreads();
        if (tid == 0) {
            double mean = (double)(wsum2[0] + wsum2[1]) / (double)NELEM_W;
            if (mean < 1e-5) mean = 1e-5;
            float mf = (float)mean;
            wsf[2] = 0.7f * mf;   // exact threshold
            wsf[3] = mf;          // exact scale
        }
    }
}

// ---------------- pass 2: exception fixup (patch unscaled gpart half 0) --------
__global__ __launch_bounds__(128) void fixup_kernel(const unsigned int* __restrict__ excg,
                                                    const float* __restrict__ w,
                                                    const float* __restrict__ spart,
                                                    const float* __restrict__ wsf,
                                                    const unsigned int* __restrict__ exc_cnt,
                                                    const __bf16* __restrict__ xb,
                                                    float* __restrict__ gpart) {
    __shared__ float thbuf[128];
    const float th  = thr_hat_from(block_sample_sum(spart, thbuf, threadIdx.x));
    const float thr = wsf[2];
    unsigned n = *exc_cnt;
    if (n > EXC_CAP) n = EXC_CAP;
    for (unsigned g = blockIdx.x * 128 + threadIdx.x; g < n; g += gridDim.x * 128) {
        unsigned e = excg[g];
        float v = w[e];                       // e == row*4096+col == linear index
        float a = __builtin_fabsf(v);
        bool qt = a > thr;   // true decision
        bool qh = a > th;    // decision the gemm used
        if (qt != qh) {
            float sgn = (__float_as_uint(v) & 0x80000000u) ? -1.0f : 1.0f;
            float d   = qt ? sgn : -sgn;
            unsigned o = e >> 12;
            unsigned i = e & 4095u;
            const __bf16* xp = xb + i;
            for (int t = 0; t < TOKENS; ++t)
                atomicAdd(&gpart[(size_t)t * OUT_F + o], d * (float)xp[(size_t)t * IN_F]);
        }
    }
}

// ---------------- pass 3: combine split-K halves + scale ----------------
__global__ __launch_bounds__(256) void combine_kernel(const float* __restrict__ gpart,
                                                      const float* __restrict__ wsf,
                                                      float* __restrict__ out) {
    const float sc = wsf[3];
    int i = blockIdx.x * 256 + threadIdx.x;   // float4 index, 88064 total
    const float4* p0 = (const float4*)gpart;
    const float4* p1 = (const float4*)(gpart + OUT_ELEMS);
    float4 a = p0[i], b = p1[i];
    float4 o;
    o.x = (a.x + b.x) * sc;
    o.y = (a.y + b.y) * sc;
    o.z = (a.z + b.z) * sc;
    o.w = (a.w + b.w) * sc;
    ((float4*)out)[i] = o;
}

extern "C" void kernel_launch(void* const* d_in, const int* in_sizes, int n_in,
                              void* d_out, int out_size, void* d_ws, size_t ws_size,
                              hipStream_t stream) {
    const float* x = (const float*)d_in[0];   // [32, 4096]
    const float* w = (const float*)d_in[1];   // [11008, 4096]
    float* out     = (float*)d_out;           // [32, 11008]
    char* ws       = (char*)d_ws;

    unsigned int* wsu   = (unsigned int*)ws;
    float*        wsf   = (float*)ws;
    uint4*        xb    = (uint4*)(ws + XB_OFF);
    float*        sprt  = (float*)(ws + SPART_OFF);
    float*        apart = (float*)(ws + APART_OFF);
    float*        gpart = (float*)(ws + GPART_OFF);
    unsigned int* excg  = (unsigned int*)(ws + EXC_OFF);

    sample_xcvt_kernel<<<320, 256, 0, stream>>>(w, x, sprt, xb, wsu + 0, wsu + 1);
    ternary_gemm<<<GEMM_BLOCKS, 128, 0, stream>>>(w, sprt, (const __bf16*)(ws + XB_OFF),
                                                  gpart, apart, excg, wsu + 0, wsu + 1, wsf);
    fixup_kernel<<<256, 128, 0, stream>>>(excg, w, sprt, wsf, wsu + 0,
                                          (const __bf16*)(ws + XB_OFF), gpart);
    combine_kernel<<<344, 256, 0, stream>>>(gpart, wsf, out);
}

// Round 3
// 439.896 us; speedup vs baseline: 1.2041x; 1.2041x over previous
//
#include <hip/hip_runtime.h>
#include <hip/hip_bf16.h>
#include <stdint.h>

#define IN_F 4096
#define OUT_F 11008
#define TOKENS 32
#define NELEM_W (OUT_F * IN_F)        // 45088768 weights, ~180 MB fp32
#define OUT_ELEMS (TOKENS * OUT_F)    // 352256

typedef __attribute__((ext_vector_type(8))) __bf16 bf16x8;
typedef __attribute__((ext_vector_type(4))) float  f32x4;

// d_ws layout (bytes):
//   [0, 64):     scalars: u[0]=exc_count, f[2]=thr (exact), f[3]=scale (exact)
//   [64,+256K):  xb — x converted to bf16
//   [262208):    spart — 256 sample-pass per-block partials (plain stores)
//   [263232):    apart — 1376 per-gemm-block sum(|w|) partials
//   [268736):    gpart — 2 x 352256 f32 split-K partials (fixup patches half 0)
//   [3086784):   exception buffer: uint32 float4-index (row*1024 + col/4), 4 MB
#define XB_OFF    64
#define SPART_OFF 262208
#define APART_OFF 263232
#define GPART_OFF 268736
#define EXC_OFF   3086784
#define EXC_CAP   1048576u

#define N_SAMPLE_F 1048576.0f   // sample kernel reads exactly 2^20 weights
#define DELTA 0.004f            // band half-width ~5 sigma of thr_hat error
#define GEMM_BLOCKS 1376

// fp32 -> bf16 bits (round-to-nearest-even), result in low 16
__device__ __forceinline__ uint32_t bfr(float v) {
    uint32_t u = __float_as_uint(v);
    uint32_t r = u + 0x7FFFu + ((u >> 16) & 1u);
    return r >> 16;
}

// provisional threshold from sampled |w| sum — must be bit-identical in
// gemm and fixup: both call the same reduction + this on the same partials.
__device__ __forceinline__ float thr_hat_from(float ssum) {
    float m = ssum * (1.0f / N_SAMPLE_F);
    if (m < 1e-5f) m = 1e-5f;
    return 0.7f * m;
}

// Deterministic reduction of the 256 sample partials for a 128-thread block.
// Fixed shuffle tree + fixed final add order -> bit-identical in every block
// of every kernel that calls it. One barrier only.
__device__ __forceinline__ float block_sample_sum128(const float* __restrict__ spart,
                                                     int tid) {
    __shared__ float bss[2];
    int lane = tid & 63;
    int wv   = tid >> 6;
    float s = spart[tid] + spart[tid + 128];
    for (int off = 32; off > 0; off >>= 1) s += __shfl_down(s, off, 64);
    if (lane == 0) bss[wv] = s;
    __syncthreads();
    return bss[0] + bss[1];
}

// ---------------- pass 0: sampled partials + x->bf16 + counter zeroing ---------
__global__ __launch_bounds__(256) void sample_xcvt_kernel(const float* __restrict__ w,
                                                          const float* __restrict__ x,
                                                          float* __restrict__ spart,
                                                          uint4* __restrict__ xb,
                                                          unsigned int* __restrict__ exc_cnt) {
    if (blockIdx.x >= 256) {
        if (blockIdx.x == 256 && threadIdx.x == 0) *exc_cnt = 0u;
        int i = (blockIdx.x - 256) * 256 + threadIdx.x;
        const float4* x4 = (const float4*)x;
        float4 a0 = x4[i * 2];
        float4 a1 = x4[i * 2 + 1];
        uint4 o;
        o.x = bfr(a0.x) | (bfr(a0.y) << 16);
        o.y = bfr(a0.z) | (bfr(a0.w) << 16);
        o.z = bfr(a1.x) | (bfr(a1.y) << 16);
        o.w = bfr(a1.z) | (bfr(a1.w) << 16);
        xb[i] = o;
        return;
    }
    const int wv   = threadIdx.x >> 6;
    const int lane = threadIdx.x & 63;
    const int wid  = blockIdx.x * 4 + wv;
    const float4* w4 = (const float4*)w;
    size_t base = (size_t)wid * 11008 + lane;
    float s = 0.f;
#pragma unroll
    for (int r = 0; r < 4; ++r) {
        float4 v = w4[base + (size_t)r * 2752];
        s += __builtin_fabsf(v.x) + __builtin_fabsf(v.y) +
             __builtin_fabsf(v.z) + __builtin_fabsf(v.w);
    }
    for (int off = 32; off > 0; off >>= 1) s += __shfl_down(s, off, 64);
    __shared__ float ws4[4];
    if (lane == 0) ws4[wv] = s;
    __syncthreads();
    if (threadIdx.x == 0) spart[blockIdx.x] = ws4[0] + ws4[1] + ws4[2] + ws4[3];
}

// ---------------- ternarize helpers ----------------
__device__ __forceinline__ uint32_t tern1(float v, float thr) {
    uint32_t u  = __float_as_uint(v);
    uint32_t pm = (u & 0x80000000u) | 0x3F800000u;   // +-1.0f
    return (__builtin_fabsf(v) > thr) ? pm : 0u;
}

__device__ __forceinline__ uint2 tern4(float4 b, float thr) {
    uint32_t q0 = tern1(b.x, thr), q1 = tern1(b.y, thr);
    uint32_t q2 = tern1(b.z, thr), q3 = tern1(b.w, thr);
    uint2 r;
    r.x = __builtin_amdgcn_perm(q1, q0, 0x07060302u);   // lo16=q0.hi16, hi16=q1.hi16
    r.y = __builtin_amdgcn_perm(q3, q2, 0x07060302u);
    return r;
}

// ---------------- pass 1: ternary GEMM — round-0 structure preserved ----------
// Grid: 688 o-groups x 2 K-halves = 1376 blocks of 128 (2 waves), all resident.
// ONLY in-loop additions vs the proven round-0 kernel: (a) sab abs-accumulate,
// (b) per-float4 band-hit bit OR'd into em_lo/em_hi (pure VALU, runtime shift,
// no arrays, no unroll pragma, no branches, no memory ops). Flush is post-loop
// with ONE global atomic per wave.
#define CHUNKS 16
#define WAVE_LDS 2304          // 16 rows * 144 B
#define SMEM_BYTES 4608        // 2 waves; also covers 2*512*4 reduce buf

__global__ __launch_bounds__(128, 4) void ternary_gemm(const float* __restrict__ w,
                                                       const float* __restrict__ spart,
                                                       const __bf16* __restrict__ xb,
                                                       float* __restrict__ gpart,
                                                       float* __restrict__ apart,
                                                       unsigned int* __restrict__ excg,
                                                       unsigned int* __restrict__ exc_cnt) {
    __shared__ char smem_raw[SMEM_BYTES];
    __shared__ float wsum2[2];

    const int og   = blockIdx.x >> 1;
    const int kh   = blockIdx.x & 1;
    const int tid  = threadIdx.x;
    const int wv   = tid >> 6;
    const int lane = tid & 63;
    const int col  = lane & 15;     // fragment: output col in group / token
    const int quad = lane >> 4;     // fragment k sub-block; staging row group
    const int rlan = lane & 15;     // staging: 16-B slot within a row

    const int kw    = kh * 2048 + wv * 1024;
    const int obase = og * 16 + quad;          // row for r=0; +4r for r=1..3

    const float* wp = w + (size_t)obase * IN_F + kw + rlan * 4;
    char* stage = smem_raw + wv * WAVE_LDS;
    char* wr    = stage + quad * 144 + rlan * 8;   // + j*576 per staging instr
    const char* rd = stage + col * 144;
    const __bf16* xq = xb + (size_t)col * IN_F + kw + quad * 8;

    f32x4 acc0 = {0.f, 0.f, 0.f, 0.f};
    f32x4 acc1 = {0.f, 0.f, 0.f, 0.f};
    float sab = 0.f;
    uint32_t em_lo = 0u, em_hi = 0u;

    float4 wb[2][4];
    bf16x8 xv[2][4];

    // issue first prefetches, THEN the 1-barrier th reduction (latency hidden)
#pragma unroll
    for (int c = 0; c < 2; ++c) {
        const float*  np = wp + c * 64;
        const __bf16* xn = xq + c * 64;
        wb[c][0] = *(const float4*)(np);
        wb[c][1] = *(const float4*)(np + 4 * IN_F);
        wb[c][2] = *(const float4*)(np + 8 * IN_F);
        wb[c][3] = *(const float4*)(np + 12 * IN_F);
        xv[c][0] = *(const bf16x8*)(xn);
        xv[c][1] = *(const bf16x8*)(xn + 32);
        xv[c][2] = *(const bf16x8*)(xn + 16 * IN_F);
        xv[c][3] = *(const bf16x8*)(xn + 16 * IN_F + 32);
    }

    const float th  = thr_hat_from(block_sample_sum128(spart, tid));
    const float eps = th * DELTA;

// per-float4 band-hit bit rr (pure VALU, bitwise | to avoid branches)
#define PROC4(vv, rr)                                                          \
    {                                                                          \
        float ax_ = __builtin_fabsf(vv.x), ay_ = __builtin_fabsf(vv.y);        \
        float az_ = __builtin_fabsf(vv.z), aw_ = __builtin_fabsf(vv.w);        \
        sab += ax_ + ay_ + az_ + aw_;                                          \
        int h_ = (__builtin_fabsf(ax_ - th) < eps) | (__builtin_fabsf(ay_ - th) < eps) | \
                 (__builtin_fabsf(az_ - th) < eps) | (__builtin_fabsf(aw_ - th) < eps);  \
        m4_ |= ((unsigned)h_) << (rr);                                         \
    }

#define GEMM_BODY(c, cur)                                                      \
    {                                                                          \
        uint2 t0 = tern4(wb[cur][0], th);                                      \
        uint2 t1 = tern4(wb[cur][1], th);                                      \
        uint2 t2 = tern4(wb[cur][2], th);                                      \
        uint2 t3 = tern4(wb[cur][3], th);                                      \
        *(uint2*)(wr)        = t0;                                             \
        *(uint2*)(wr + 576)  = t1;                                             \
        *(uint2*)(wr + 1152) = t2;                                             \
        *(uint2*)(wr + 1728) = t3;                                             \
        unsigned m4_ = 0u;                                                     \
        PROC4(wb[cur][0], 0)                                                   \
        PROC4(wb[cur][1], 1)                                                   \
        PROC4(wb[cur][2], 2)                                                   \
        PROC4(wb[cur][3], 3)                                                   \
        unsigned sh_ = ((unsigned)(c) * 4u) & 31u;                             \
        unsigned tt_ = m4_ << sh_;                                             \
        if ((c) < 8) em_lo |= tt_; else em_hi |= tt_;                          \
        bf16x8 a00 = xv[cur][0], a01 = xv[cur][1];                             \
        bf16x8 a10 = xv[cur][2], a11 = xv[cur][3];                             \
        if ((c) + 2 < CHUNKS) {                                                \
            const float*  np = wp + ((c) + 2) * 64;                            \
            const __bf16* xn = xq + ((c) + 2) * 64;                            \
            wb[cur][0] = *(const float4*)(np);                                 \
            wb[cur][1] = *(const float4*)(np + 4 * IN_F);                      \
            wb[cur][2] = *(const float4*)(np + 8 * IN_F);                      \
            wb[cur][3] = *(const float4*)(np + 12 * IN_F);                     \
            xv[cur][0] = *(const bf16x8*)(xn);                                 \
            xv[cur][1] = *(const bf16x8*)(xn + 32);                            \
            xv[cur][2] = *(const bf16x8*)(xn + 16 * IN_F);                     \
            xv[cur][3] = *(const bf16x8*)(xn + 16 * IN_F + 32);                \
        }                                                                      \
        bf16x8 bw0 = *(const bf16x8*)(rd + quad * 16);                         \
        bf16x8 bw1 = *(const bf16x8*)(rd + 64 + quad * 16);                    \
        acc0 = __builtin_amdgcn_mfma_f32_16x16x32_bf16(a00, bw0, acc0, 0, 0, 0); \
        acc1 = __builtin_amdgcn_mfma_f32_16x16x32_bf16(a10, bw0, acc1, 0, 0, 0); \
        acc0 = __builtin_amdgcn_mfma_f32_16x16x32_bf16(a01, bw1, acc0, 0, 0, 0); \
        acc1 = __builtin_amdgcn_mfma_f32_16x16x32_bf16(a11, bw1, acc1, 0, 0, 0); \
    }

    for (int c = 0; c < CHUNKS; c += 2) {
        GEMM_BODY(c, 0)
        GEMM_BODY(c + 1, 1)
    }
#undef GEMM_BODY
#undef PROC4

    // exact |w| partial: wave shuffle reduce, cross-wave via LDS
    for (int off = 32; off > 0; off >>= 1) sab += __shfl_down(sab, off, 64);
    if (lane == 0) wsum2[wv] = sab;

    __syncthreads();                 // guards wsum2 AND smem_raw reuse below
    if (tid == 0) apart[blockIdx.x] = wsum2[0] + wsum2[1];

    float* red   = (float*)smem_raw;
    float* basef = red + wv * 512;
#pragma unroll
    for (int r = 0; r < 4; ++r) basef[r * 64 + lane]       = acc0[r];
#pragma unroll
    for (int r = 0; r < 4; ++r) basef[256 + r * 64 + lane] = acc1[r];
    __syncthreads();

    // 512 outputs (32 tokens x 16 cols), summed over 2 waves
    float* gp = gpart + (size_t)kh * OUT_ELEMS;
    for (int p = tid; p < 512; p += 128) {
        int t = p >> 4, cc2 = p & 15;
        int a = t >> 4;
        int q = (t >> 2) & 3;
        int r = t & 3;
        int idx = a * 256 + r * 64 + q * 16 + cc2;
        gp[(size_t)t * OUT_F + og * 16 + cc2] = red[idx] + red[512 + idx];
    }

    // flush exception float4-indices: wave prefix scan, ONE atomic per wave
    unsigned cnt = (unsigned)(__popc(em_lo) + __popc(em_hi));
    unsigned pre = cnt;
#pragma unroll
    for (int off = 1; off < 64; off <<= 1) {
        unsigned t = __shfl_up(pre, off, 64);
        if (lane >= off) pre += t;
    }
    unsigned total = __shfl(pre, 63, 64);
    unsigned wbase = 0u;
    if (lane == 63) wbase = total ? atomicAdd(exc_cnt, total) : 0u;
    wbase = __shfl(wbase, 63, 64);
    unsigned pos = wbase + pre - cnt;
    unsigned m = em_lo;
    while (m) {
        int b = __ffs(m) - 1; m &= m - 1;
        int cc3 = b >> 2, rr = b & 3;
        unsigned idx4 = (unsigned)(obase + 4 * rr) * 1024u +
                        (unsigned)((kw >> 2) + cc3 * 16 + rlan);
        if (pos < EXC_CAP) excg[pos] = idx4;
        ++pos;
    }
    m = em_hi;
    while (m) {
        int b = __ffs(m) - 1; m &= m - 1;
        int cc3 = 8 + (b >> 2), rr = b & 3;
        unsigned idx4 = (unsigned)(obase + 4 * rr) * 1024u +
                        (unsigned)((kw >> 2) + cc3 * 16 + rlan);
        if (pos < EXC_CAP) excg[pos] = idx4;
        ++pos;
    }
}

// ---------------- pass 2: exact mean -> thr/scale ----------------
__global__ __launch_bounds__(256) void finalize_kernel(const float* __restrict__ apart,
                                                       float* __restrict__ wsf) {
    float s = 0.f;
#pragma unroll
    for (int j = 0; j < 6; ++j) {
        int k = threadIdx.x + 256 * j;
        if (k < GEMM_BLOCKS) s += apart[k];
    }
    for (int off = 32; off > 0; off >>= 1) s += __shfl_down(s, off, 64);
    __shared__ float wsum[4];
    int lane = threadIdx.x & 63;
    int wv   = threadIdx.x >> 6;
    if (lane == 0) wsum[wv] = s;
    __syncthreads();
    if (threadIdx.x == 0) {
        double mean = (double)(wsum[0] + wsum[1] + wsum[2] + wsum[3]) / (double)NELEM_W;
        if (mean < 1e-5) mean = 1e-5;
        float mf = (float)mean;
        wsf[2] = 0.7f * mf;   // exact threshold
        wsf[3] = mf;          // exact scale
    }
}

// ---------------- pass 3: exception fixup (patch unscaled gpart half 0) --------
__global__ __launch_bounds__(128) void fixup_kernel(const unsigned int* __restrict__ excg,
                                                    const float* __restrict__ w,
                                                    const float* __restrict__ spart,
                                                    const float* __restrict__ wsf,
                                                    const unsigned int* __restrict__ exc_cnt,
                                                    const __bf16* __restrict__ xb,
                                                    float* __restrict__ gpart) {
    const float th  = thr_hat_from(block_sample_sum128(spart, (int)threadIdx.x));
    const float thr = wsf[2];
    unsigned n = *exc_cnt;
    if (n > EXC_CAP) n = EXC_CAP;
    const float4* w4 = (const float4*)w;
    for (unsigned g = blockIdx.x * 128 + threadIdx.x; g < n; g += gridDim.x * 128) {
        unsigned idx4 = excg[g];
        float4 v4 = w4[idx4];
        unsigned o     = idx4 >> 10;
        unsigned ibase = (idx4 & 1023u) * 4u;
        float el[4] = {v4.x, v4.y, v4.z, v4.w};
#pragma unroll
        for (int e = 0; e < 4; ++e) {
            float v = el[e];
            float a = __builtin_fabsf(v);
            bool qt = a > thr;   // true decision
            bool qh = a > th;    // decision the gemm used
            if (qt != qh) {
                float sgn = (__float_as_uint(v) & 0x80000000u) ? -1.0f : 1.0f;
                float d   = qt ? sgn : -sgn;
                const __bf16* xp = xb + (ibase + e);
                for (int t = 0; t < TOKENS; ++t)
                    atomicAdd(&gpart[(size_t)t * OUT_F + o], d * (float)xp[(size_t)t * IN_F]);
            }
        }
    }
}

// ---------------- pass 4: combine split-K halves + scale ----------------
__global__ __launch_bounds__(256) void combine_kernel(const float* __restrict__ gpart,
                                                      const float* __restrict__ wsf,
                                                      float* __restrict__ out) {
    const float sc = wsf[3];
    int i = blockIdx.x * 256 + threadIdx.x;   // float4 index, 88064 total
    const float4* p0 = (const float4*)gpart;
    const float4* p1 = (const float4*)(gpart + OUT_ELEMS);
    float4 a = p0[i], b = p1[i];
    float4 o;
    o.x = (a.x + b.x) * sc;
    o.y = (a.y + b.y) * sc;
    o.z = (a.z + b.z) * sc;
    o.w = (a.w + b.w) * sc;
    ((float4*)out)[i] = o;
}

extern "C" void kernel_launch(void* const* d_in, const int* in_sizes, int n_in,
                              void* d_out, int out_size, void* d_ws, size_t ws_size,
                              hipStream_t stream) {
    const float* x = (const float*)d_in[0];   // [32, 4096]
    const float* w = (const float*)d_in[1];   // [11008, 4096]
    float* out     = (float*)d_out;           // [32, 11008]
    char* ws       = (char*)d_ws;

    unsigned int* wsu   = (unsigned int*)ws;
    float*        wsf   = (float*)ws;
    uint4*        xb    = (uint4*)(ws + XB_OFF);
    float*        sprt  = (float*)(ws + SPART_OFF);
    float*        apart = (float*)(ws + APART_OFF);
    float*        gpart = (float*)(ws + GPART_OFF);
    unsigned int* excg  = (unsigned int*)(ws + EXC_OFF);

    sample_xcvt_kernel<<<320, 256, 0, stream>>>(w, x, sprt, xb, wsu + 0);
    ternary_gemm<<<GEMM_BLOCKS, 128, 0, stream>>>(w, sprt, (const __bf16*)(ws + XB_OFF),
                                                  gpart, apart, excg, wsu + 0);
    finalize_kernel<<<1, 256, 0, stream>>>(apart, wsf);
    fixup_kernel<<<512, 128, 0, stream>>>(excg, w, sprt, wsf, wsu + 0,
                                          (const __bf16*)(ws + XB_OFF), gpart);
    combine_kernel<<<344, 256, 0, stream>>>(gpart, wsf, out);
}